// Round 7
// baseline (3846.542 us; speedup 1.0000x reference)
//
#include <hip/hip_runtime.h>
#include <cstdint>
#include <cstddef>

// LSTM: BS=64, H=512, T=256.  Round 5: 4 independent 16-sample groups x 8
// col-split blocks; h + flags exchanged via relaxed SYSTEM-scope (sc0 sc1)
// accesses through IC -- no fences, V stays L2-resident.

typedef _Float16 f16;
typedef _Float16 f16x8 __attribute__((ext_vector_type(8)));
typedef float f32x4 __attribute__((ext_vector_type(4)));
typedef unsigned int u32;

#define BS 64
#define H  512
#define TSTEPS 256
#define KTOT 1024
#define GCOLS 2048
#define HSLOT (BS * H)          // f16 per time slot
#define HSLOT32 (HSLOT / 2)     // dwords per slot = 16384

// ---- static device scratch ----
__device__ f16  g_W16T[(size_t)GCOLS * KTOT];          // 4 MB: W^T[col][k] (k<512=U, >=512=V)
__device__ f16  g_xT[(size_t)TSTEPS * HSLOT];          // 16 MB
__device__ u32  g_hbuf32[(size_t)(TSTEPS + 1) * HSLOT32]; // 16.8 MB, dword view
__device__ float g_XU[(size_t)TSTEPS * BS * GCOLS];    // 128 MB: x@U + bias
__device__ int  g_flags[4][16];                        // per-group epoch flags

__global__ void prep_zero() {
  int i = blockIdx.x * 256 + threadIdx.x;
  if (i < HSLOT32) g_hbuf32[i] = 0u;
  if (i < 64) ((int*)g_flags)[i] = 0;
}

// ---- W16T[col][k] = (k<512 ? U[k][col] : V[k-512][col]) as fp16 ----
__global__ void build_w16t(const float* __restrict__ U, const float* __restrict__ V) {
  __shared__ float tile[32][33];
  int colT = blockIdx.x, kT = blockIdx.y;
  int x = threadIdx.x & 31, y = threadIdx.x >> 5;
  int col0 = colT * 32, k0 = kT * 32;
  for (int yy = y; yy < 32; yy += 8) {
    int k = k0 + yy;
    float v = (k < H) ? U[(size_t)k * GCOLS + col0 + x]
                      : V[(size_t)(k - H) * GCOLS + col0 + x];
    tile[yy][x] = v;
  }
  __syncthreads();
  for (int yy = y; yy < 32; yy += 8)
    g_W16T[(size_t)(col0 + yy) * KTOT + k0 + x] = (f16)tile[x][yy];
}

// ---- xT16[t][b][k] = x[b][k][t] as fp16 ----
__global__ void build_xt16(const float* __restrict__ x) {
  __shared__ float tile[32][33];
  int kt = blockIdx.x, tt = blockIdx.y, b = blockIdx.z;
  int xl = threadIdx.x & 31, y = threadIdx.x >> 5;
  int k0 = kt * 32, t0 = tt * 32;
  for (int yy = y; yy < 32; yy += 8)
    tile[yy][xl] = x[(size_t)b * (H * TSTEPS) + (size_t)(k0 + yy) * TSTEPS + t0 + xl];
  __syncthreads();
  for (int yy = y; yy < 32; yy += 8)
    g_xT[((size_t)(t0 + yy) * BS + b) * H + k0 + xl] = (f16)tile[xl][yy];
}

// ---- XU GEMM: g_XU[m][n] = xT[m][:512] @ U + bias.  Wave = 16 rows x 64
// cols (4 C-tiles share one A-frag per k-step). Grid (256, 32) x 256 thr.
__global__ void xu_gemm(const float* __restrict__ bias) {
  const int tid  = threadIdx.x;
  const int lane = tid & 63;
  const int wv   = tid >> 6;
  const int l16  = lane & 15;
  const int lk8  = (lane >> 4) * 8;
  const int m0 = blockIdx.x * 64 + wv * 16;
  const int n0 = blockIdx.y * 64;

  const f16* Ap = g_xT + (size_t)(m0 + l16) * H + lk8;
  size_t bb[4];
  #pragma unroll
  for (int c = 0; c < 4; ++c)
    bb[c] = (size_t)(n0 + c * 16 + l16) * KTOT + lk8;

  f32x4 acc[4] = {};
  #pragma unroll 4
  for (int ki = 0; ki < 16; ++ki) {
    f16x8 a = *(const f16x8*)(Ap + ki * 32);
    #pragma unroll
    for (int c = 0; c < 4; ++c) {
      f16x8 b = *(const f16x8*)(g_W16T + bb[c] + ki * 32);
      acc[c] = __builtin_amdgcn_mfma_f32_16x16x32_f16(a, b, acc[c], 0, 0, 0);
    }
  }
  #pragma unroll
  for (int c = 0; c < 4; ++c) {
    float bv = bias[n0 + c * 16 + l16];
    #pragma unroll
    for (int i = 0; i < 4; ++i) {
      int m = m0 + (lane >> 4) * 4 + i;   // C/D: row=(lane>>4)*4+i, col=l16
      g_XU[(size_t)m * GCOLS + n0 + c * 16 + l16] = acc[c][i] + bv;
    }
  }
}

// ---------------- persistent recurrent kernel ----------------
// 32 blocks x 256 thr. grp = bid>>3 (16 samples), cb = bid&7 (64 units).
// Wave w: units u0+w*16..+16, all 4 gates (4 C-tiles), K=512 (V half).
// Lane holds (sample=(lane>>4)*4+i, unit=u0+w*16+(lane&15)) for all gates
// -> nonlinearity fully in-register; c in registers.
__launch_bounds__(256, 1)
__global__ void lstm_rec(float* __restrict__ out_cT) {
  __shared__ __align__(16) char h_stage[16 * 1024];  // swizzled [16][512] f16
  __shared__ f16 h_out2[16][64];                     // [sample][unit-in-block]

  const int tid  = threadIdx.x;
  const int lane = tid & 63;
  const int wv   = tid >> 6;
  const int l16  = lane & 15;
  const int lk16 = (lane >> 4) * 16;     // byte offset of k-subgroup (8 f16)
  const int grp  = blockIdx.x >> 3;
  const int cb   = blockIdx.x & 7;
  const int u0   = cb * 64;

  // B (V) pointers: col = g*512 + u0 + wv*16 + l16, k = 512 + lk16/2 + ki*32
  size_t boff[4];
  #pragma unroll
  for (int g = 0; g < 4; ++g)
    boff[g] = (size_t)(g * H + u0 + wv * 16 + l16) * KTOT + H + lk16 / 2;

  float c4[4] = {0.f, 0.f, 0.f, 0.f};

  for (int t = 0; t < TSTEPS; ++t) {
    // --- XU prefetch (independent of h[t]) ---
    float xu[4][4];
    #pragma unroll
    for (int i = 0; i < 4; ++i) {
      size_t row = (size_t)t * BS + grp * 16 + (lane >> 4) * 4 + i;
      #pragma unroll
      for (int g = 0; g < 4; ++g)
        xu[g][i] = g_XU[row * GCOLS + g * H + u0 + wv * 16 + l16];
    }

    // --- wait for h[t] from the other 7 blocks of this group ---
    if (t > 0) {
      if (wv == 0) {
        int spin = 0; bool done;
        do {
          int v = (lane < 8)
            ? __hip_atomic_load(&g_flags[grp][lane], __ATOMIC_RELAXED,
                                __HIP_MEMORY_SCOPE_SYSTEM)
            : t;
          done = __all(v >= t);
          if (!done) {
            if (++spin > (1 << 17)) break;   // safety hatch
            __builtin_amdgcn_s_sleep(1);
          }
        } while (!done);
      }
      __syncthreads();
    }

    // --- stage h[t] (16 samples x 512) into swizzled LDS via sc1 loads ---
    {
      size_t base32 = (size_t)t * HSLOT32 + grp * 4096;
      #pragma unroll
      for (int it = 0; it < 16; ++it) {
        int flat = it * 256 + tid;               // dword index in 16x256
        u32 v = __hip_atomic_load(&g_hbuf32[base32 + flat], __ATOMIC_RELAXED,
                                  __HIP_MEMORY_SCOPE_SYSTEM);
        int s = flat >> 8;                        // sample row
        int byt = (flat & 255) * 4;
        *(u32*)&h_stage[s * 1024 + (byt ^ ((s & 7) << 4))] = v;
      }
    }
    __syncthreads();

    // --- h[t] @ V : 4 gate-tiles, K=512 ---
    f32x4 acc[4] = {};
    #pragma unroll 4
    for (int ki = 0; ki < 16; ++ki) {
      int abyte = l16 * 1024 + ((ki * 64 + lk16) ^ ((l16 & 7) << 4));
      f16x8 a = *(const f16x8*)&h_stage[abyte];
      #pragma unroll
      for (int g = 0; g < 4; ++g) {
        f16x8 b = *(const f16x8*)(g_W16T + boff[g] + ki * 32);
        acc[g] = __builtin_amdgcn_mfma_f32_16x16x32_f16(a, b, acc[g], 0, 0, 0);
      }
    }

    // --- nonlinearity, in-register; h -> LDS for packing ---
    #pragma unroll
    for (int i = 0; i < 4; ++i) {
      float gi = acc[0][i] + xu[0][i];
      float gf = acc[1][i] + xu[1][i];
      float gg = acc[2][i] + xu[2][i];
      float go = acc[3][i] + xu[3][i];
      float it = 1.f / (1.f + __expf(-gi));
      float ft = 1.f / (1.f + __expf(-gf));
      float gt = tanhf(gg);
      float ot = 1.f / (1.f + __expf(-go));
      float c  = ft * c4[i] + it * gt;
      c4[i] = c;
      float hh = ot * tanhf(c);
      int s = (lane >> 4) * 4 + i;
      h_out2[s][wv * 16 + l16] = (f16)hh;
      if (t == TSTEPS - 1)
        out_cT[(size_t)(grp * 16 + s) * H + u0 + wv * 16 + l16] = c;
    }
    __syncthreads();

    // --- publish h chunk via sc1 dword stores (coalesced) ---
    {
      #pragma unroll
      for (int rep = 0; rep < 2; ++rep) {
        int flat = rep * 256 + tid;              // 512 dwords = 16 x 64 units
        int s = flat >> 5, dw = flat & 31;
        u32 v = *(const u32*)&h_out2[s][dw * 2];
        size_t idx = (size_t)(t + 1) * HSLOT32 + (size_t)(grp * 16 + s) * 256
                   + (u0 >> 1) + dw;
        __hip_atomic_store(&g_hbuf32[idx], v, __ATOMIC_RELAXED,
                           __HIP_MEMORY_SCOPE_SYSTEM);
      }
    }
    __syncthreads();   // drains vmcnt: sc1 stores are at IC
    if (tid == 0)
      __hip_atomic_store(&g_flags[grp][cb], t + 1, __ATOMIC_RELAXED,
                         __HIP_MEMORY_SCOPE_SYSTEM);
  }
}

// ---- finalize: out[b][j][t] = hbuf[t+1][b][j] ----
__global__ void finalize_seq(float* __restrict__ out) {
  __shared__ float tile[32][33];
  const f16* hb = (const f16*)g_hbuf32;
  int jt = blockIdx.x, tt = blockIdx.y, b = blockIdx.z;
  int xl = threadIdx.x & 31, y = threadIdx.x >> 5;
  int j0 = jt * 32, t0 = tt * 32;
  for (int yy = y; yy < 32; yy += 8)
    tile[yy][xl] = (float)hb[(size_t)(t0 + yy + 1) * HSLOT + (size_t)b * H + j0 + xl];
  __syncthreads();
  for (int yy = y; yy < 32; yy += 8)
    out[(size_t)b * (H * TSTEPS) + (size_t)(j0 + yy) * TSTEPS + t0 + xl] = tile[xl][yy];
}

__global__ void copy_hT(float* __restrict__ out_hT) {
  const f16* hb = (const f16*)g_hbuf32;
  int i = blockIdx.x * 256 + threadIdx.x;
  if (i < HSLOT) out_hT[i] = (float)hb[(size_t)TSTEPS * HSLOT + i];
}

// ---------------- host ----------------
extern "C" void kernel_launch(void* const* d_in, const int* in_sizes, int n_in,
                              void* d_out, int out_size, void* d_ws, size_t ws_size,
                              hipStream_t stream) {
  (void)in_sizes; (void)n_in; (void)d_ws; (void)ws_size; (void)out_size;
  const float* x    = (const float*)d_in[0];
  const float* U    = (const float*)d_in[1];
  const float* V    = (const float*)d_in[2];
  const float* bias = (const float*)d_in[3];
  float* out = (float*)d_out;

  float* out_hT = out + (size_t)BS * H * TSTEPS;
  float* out_cT = out_hT + (size_t)BS * H;

  prep_zero<<<dim3(65), dim3(256), 0, stream>>>();
  build_w16t<<<dim3(64, 32), dim3(256), 0, stream>>>(U, V);
  build_xt16<<<dim3(16, 8, 64), dim3(256), 0, stream>>>(x);
  xu_gemm<<<dim3(256, 32), dim3(256), 0, stream>>>(bias);
  lstm_rec<<<dim3(32), dim3(256), 0, stream>>>(out_cT);
  finalize_seq<<<dim3(16, 8, 64), dim3(256), 0, stream>>>(out);
  copy_hT<<<dim3(128), dim3(256), 0, stream>>>(out_hT);
}

// Round 8
// 2950.903 us; speedup vs baseline: 1.3035x; 1.3035x over previous
//
#include <hip/hip_runtime.h>
#include <cstdint>
#include <cstddef>

// LSTM: BS=64, H=512, T=256.  Round 8: round-7 structure (4 independent
// 16-sample groups x 8 col-split blocks, sc0/sc1 IC-coherent h exchange)
// but with BATCHED bypass loads/stores: one vmcnt drain per exchange
// instead of 16 serialized atomic round-trips.

typedef _Float16 f16;
typedef _Float16 f16x8 __attribute__((ext_vector_type(8)));
typedef float f32x4 __attribute__((ext_vector_type(4)));
typedef unsigned int u32;
typedef unsigned int u32x2 __attribute__((ext_vector_type(2)));
typedef unsigned int u32x4 __attribute__((ext_vector_type(4)));

#define BS 64
#define H  512
#define TSTEPS 256
#define KTOT 1024
#define GCOLS 2048
#define HSLOT (BS * H)          // f16 per time slot
#define HSLOT32 (HSLOT / 2)     // dwords per slot = 16384

// ---- static device scratch ----
__device__ f16  g_W16T[(size_t)GCOLS * KTOT];          // 4 MB: W^T[col][k] (k<512=U, >=512=V)
__device__ f16  g_xT[(size_t)TSTEPS * HSLOT];          // 16 MB
__device__ u32  g_hbuf32[(size_t)(TSTEPS + 1) * HSLOT32]; // 16.8 MB, dword view
__device__ float g_XU[(size_t)TSTEPS * BS * GCOLS];    // 128 MB: x@U + bias
__device__ int  g_flags[4][16];                        // per-group epoch flags

__global__ void prep_zero() {
  int i = blockIdx.x * 256 + threadIdx.x;
  if (i < HSLOT32) g_hbuf32[i] = 0u;
  if (i < 64) ((int*)g_flags)[i] = 0;
}

// ---- W16T[col][k] = (k<512 ? U[k][col] : V[k-512][col]) as fp16 ----
__global__ void build_w16t(const float* __restrict__ U, const float* __restrict__ V) {
  __shared__ float tile[32][33];
  int colT = blockIdx.x, kT = blockIdx.y;
  int x = threadIdx.x & 31, y = threadIdx.x >> 5;
  int col0 = colT * 32, k0 = kT * 32;
  for (int yy = y; yy < 32; yy += 8) {
    int k = k0 + yy;
    float v = (k < H) ? U[(size_t)k * GCOLS + col0 + x]
                      : V[(size_t)(k - H) * GCOLS + col0 + x];
    tile[yy][x] = v;
  }
  __syncthreads();
  for (int yy = y; yy < 32; yy += 8)
    g_W16T[(size_t)(col0 + yy) * KTOT + k0 + x] = (f16)tile[x][yy];
}

// ---- xT16[t][b][k] = x[b][k][t] as fp16 ----
__global__ void build_xt16(const float* __restrict__ x) {
  __shared__ float tile[32][33];
  int kt = blockIdx.x, tt = blockIdx.y, b = blockIdx.z;
  int xl = threadIdx.x & 31, y = threadIdx.x >> 5;
  int k0 = kt * 32, t0 = tt * 32;
  for (int yy = y; yy < 32; yy += 8)
    tile[yy][xl] = x[(size_t)b * (H * TSTEPS) + (size_t)(k0 + yy) * TSTEPS + t0 + xl];
  __syncthreads();
  for (int yy = y; yy < 32; yy += 8)
    g_xT[((size_t)(t0 + yy) * BS + b) * H + k0 + xl] = (f16)tile[xl][yy];
}

// ---- XU GEMM: g_XU[m][n] = xT[m][:512] @ U + bias ----
__global__ void xu_gemm(const float* __restrict__ bias) {
  const int tid  = threadIdx.x;
  const int lane = tid & 63;
  const int wv   = tid >> 6;
  const int l16  = lane & 15;
  const int lk8  = (lane >> 4) * 8;
  const int m0 = blockIdx.x * 64 + wv * 16;
  const int n0 = blockIdx.y * 64;

  const f16* Ap = g_xT + (size_t)(m0 + l16) * H + lk8;
  size_t bb[4];
  #pragma unroll
  for (int c = 0; c < 4; ++c)
    bb[c] = (size_t)(n0 + c * 16 + l16) * KTOT + lk8;

  f32x4 acc[4] = {};
  #pragma unroll 4
  for (int ki = 0; ki < 16; ++ki) {
    f16x8 a = *(const f16x8*)(Ap + ki * 32);
    #pragma unroll
    for (int c = 0; c < 4; ++c) {
      f16x8 b = *(const f16x8*)(g_W16T + bb[c] + ki * 32);
      acc[c] = __builtin_amdgcn_mfma_f32_16x16x32_f16(a, b, acc[c], 0, 0, 0);
    }
  }
  #pragma unroll
  for (int c = 0; c < 4; ++c) {
    float bv = bias[n0 + c * 16 + l16];
    #pragma unroll
    for (int i = 0; i < 4; ++i) {
      int m = m0 + (lane >> 4) * 4 + i;   // C/D: row=(lane>>4)*4+i, col=l16
      g_XU[(size_t)m * GCOLS + n0 + c * 16 + l16] = acc[c][i] + bv;
    }
  }
}

// ---------------- persistent recurrent kernel ----------------
// 32 blocks x 256 thr. grp = bid>>3 (16 samples), cb = bid&7 (64 units).
// Wave w: units u0+w*16..+16, all 4 gates (4 C-tiles), K=512 (V half).
__launch_bounds__(256, 1)
__global__ void lstm_rec(float* __restrict__ out_cT) {
  __shared__ __align__(16) char h_stage[16 * 1024];  // swizzled [16][512] f16
  __shared__ f16 h_out2[16][64];                     // [sample][unit-in-block]

  const int tid  = threadIdx.x;
  const int lane = tid & 63;
  const int wv   = tid >> 6;
  const int l16  = lane & 15;
  const int lk16 = (lane >> 4) * 16;     // byte offset of k-subgroup (8 f16)
  const int grp  = blockIdx.x >> 3;
  const int cb   = blockIdx.x & 7;
  const int u0   = cb * 64;

  size_t boff[4];
  #pragma unroll
  for (int g = 0; g < 4; ++g)
    boff[g] = (size_t)(g * H + u0 + wv * 16 + l16) * KTOT + H + lk16 / 2;

  float c4[4] = {0.f, 0.f, 0.f, 0.f};

  for (int t = 0; t < TSTEPS; ++t) {
    // --- XU prefetch (independent of h[t]; hides under the poll) ---
    float xu[4][4];
    #pragma unroll
    for (int i = 0; i < 4; ++i) {
      size_t row = (size_t)t * BS + grp * 16 + (lane >> 4) * 4 + i;
      #pragma unroll
      for (int g = 0; g < 4; ++g)
        xu[g][i] = g_XU[row * GCOLS + g * H + u0 + wv * 16 + l16];
    }

    // --- wait for h[t] from the other blocks of this group ---
    if (t > 0) {
      if (wv == 0) {
        int spin = 0; bool done;
        do {
          int v = (lane < 8)
            ? __hip_atomic_load(&g_flags[grp][lane], __ATOMIC_RELAXED,
                                __HIP_MEMORY_SCOPE_SYSTEM)
            : t;
          done = __all(v >= t);
          if (!done) {
            if (++spin > (1 << 17)) break;   // safety hatch
            __builtin_amdgcn_s_sleep(1);
          }
        } while (!done);
      }
      __syncthreads();
    }

    // --- stage h[t] (16 KB) via BATCHED bypass loads: one vmcnt drain ---
    {
      size_t base32 = (size_t)t * HSLOT32 + grp * 4096;
      const u32* p0 = g_hbuf32 + base32 + (size_t)tid * 4;
      const u32* p1 = p0 + 1024;
      const u32* p2 = p0 + 2048;
      const u32* p3 = p0 + 3072;
      u32x4 d0, d1, d2, d3;
      asm volatile(
        "global_load_dwordx4 %0, %4, off sc0 sc1\n\t"
        "global_load_dwordx4 %1, %5, off sc0 sc1\n\t"
        "global_load_dwordx4 %2, %6, off sc0 sc1\n\t"
        "global_load_dwordx4 %3, %7, off sc0 sc1\n\t"
        "s_waitcnt vmcnt(0)"
        : "=&v"(d0), "=&v"(d1), "=&v"(d2), "=&v"(d3)
        : "v"(p0), "v"(p1), "v"(p2), "v"(p3)
        : "memory");
      #pragma unroll
      for (int c = 0; c < 4; ++c) {
        int flat4 = c * 256 + tid;            // 16B-chunk index (0..1023)
        int s = flat4 >> 6;                   // sample row
        int byt = (flat4 & 63) * 16;          // byte offset within row
        u32x4 d = (c == 0) ? d0 : (c == 1) ? d1 : (c == 2) ? d2 : d3;
        *(u32x4*)&h_stage[s * 1024 + (byt ^ ((s & 7) << 4))] = d;
      }
    }
    __syncthreads();

    // --- h[t] @ V : 4 gate-tiles, K=512 ---
    f32x4 acc[4] = {};
    #pragma unroll 4
    for (int ki = 0; ki < 16; ++ki) {
      int abyte = l16 * 1024 + ((ki * 64 + lk16) ^ ((l16 & 7) << 4));
      f16x8 a = *(const f16x8*)&h_stage[abyte];
      #pragma unroll
      for (int g = 0; g < 4; ++g) {
        f16x8 b = *(const f16x8*)(g_W16T + boff[g] + ki * 32);
        acc[g] = __builtin_amdgcn_mfma_f32_16x16x32_f16(a, b, acc[g], 0, 0, 0);
      }
    }

    // --- nonlinearity, in-register; h -> LDS for packing ---
    #pragma unroll
    for (int i = 0; i < 4; ++i) {
      float gi = acc[0][i] + xu[0][i];
      float gf = acc[1][i] + xu[1][i];
      float gg = acc[2][i] + xu[2][i];
      float go = acc[3][i] + xu[3][i];
      float it = 1.f / (1.f + __expf(-gi));
      float ft = 1.f / (1.f + __expf(-gf));
      float gt = tanhf(gg);
      float ot = 1.f / (1.f + __expf(-go));
      float c  = ft * c4[i] + it * gt;
      c4[i] = c;
      float hh = ot * tanhf(c);
      int s = (lane >> 4) * 4 + i;
      h_out2[s][wv * 16 + l16] = (f16)hh;
      if (t == TSTEPS - 1)
        out_cT[(size_t)(grp * 16 + s) * H + u0 + wv * 16 + l16] = c;
    }
    __syncthreads();

    // --- publish 2 KB via one bypass dwordx2 store/thread + single drain ---
    {
      int s   = tid >> 4;                    // sample row 0..15
      int dwp = (tid & 15) * 2;              // dword offset within row's chunk
      u32x2 v = *(const u32x2*)&h_out2[s][dwp * 2];
      u32* dst = g_hbuf32 + (size_t)(t + 1) * HSLOT32
               + (size_t)(grp * 16 + s) * 256 + (u0 >> 1) + dwp;
      asm volatile(
        "global_store_dwordx2 %0, %1, off sc0 sc1\n\t"
        "s_waitcnt vmcnt(0)"
        :: "v"(dst), "v"(v)
        : "memory");
    }
    __syncthreads();   // all threads' stores are at IC
    if (tid == 0)
      __hip_atomic_store(&g_flags[grp][cb], t + 1, __ATOMIC_RELAXED,
                         __HIP_MEMORY_SCOPE_SYSTEM);
  }
}

// ---- finalize: out[b][j][t] = hbuf[t+1][b][j] ----
__global__ void finalize_seq(float* __restrict__ out) {
  __shared__ float tile[32][33];
  const f16* hb = (const f16*)g_hbuf32;
  int jt = blockIdx.x, tt = blockIdx.y, b = blockIdx.z;
  int xl = threadIdx.x & 31, y = threadIdx.x >> 5;
  int j0 = jt * 32, t0 = tt * 32;
  for (int yy = y; yy < 32; yy += 8)
    tile[yy][xl] = (float)hb[(size_t)(t0 + yy + 1) * HSLOT + (size_t)b * H + j0 + xl];
  __syncthreads();
  for (int yy = y; yy < 32; yy += 8)
    out[(size_t)b * (H * TSTEPS) + (size_t)(j0 + yy) * TSTEPS + t0 + xl] = tile[xl][yy];
}

__global__ void copy_hT(float* __restrict__ out_hT) {
  const f16* hb = (const f16*)g_hbuf32;
  int i = blockIdx.x * 256 + threadIdx.x;
  if (i < HSLOT) out_hT[i] = (float)hb[(size_t)TSTEPS * HSLOT + i];
}

// ---------------- host ----------------
extern "C" void kernel_launch(void* const* d_in, const int* in_sizes, int n_in,
                              void* d_out, int out_size, void* d_ws, size_t ws_size,
                              hipStream_t stream) {
  (void)in_sizes; (void)n_in; (void)d_ws; (void)ws_size; (void)out_size;
  const float* x    = (const float*)d_in[0];
  const float* U    = (const float*)d_in[1];
  const float* V    = (const float*)d_in[2];
  const float* bias = (const float*)d_in[3];
  float* out = (float*)d_out;

  float* out_hT = out + (size_t)BS * H * TSTEPS;
  float* out_cT = out_hT + (size_t)BS * H;

  prep_zero<<<dim3(65), dim3(256), 0, stream>>>();
  build_w16t<<<dim3(64, 32), dim3(256), 0, stream>>>(U, V);
  build_xt16<<<dim3(16, 8, 64), dim3(256), 0, stream>>>(x);
  xu_gemm<<<dim3(256, 32), dim3(256), 0, stream>>>(bias);
  lstm_rec<<<dim3(32), dim3(256), 0, stream>>>(out_cT);
  finalize_seq<<<dim3(16, 8, 64), dim3(256), 0, stream>>>(out);
  copy_hT<<<dim3(128), dim3(256), 0, stream>>>(out_hT);
}

// Round 9
// 1443.895 us; speedup vs baseline: 2.6640x; 2.0437x over previous
//
#include <hip/hip_runtime.h>
#include <cstdint>
#include <cstddef>

// LSTM: BS=64, H=512, T=256.  Round 9: 4 groups x 16 blocks (16 samples x
// 32 units each).  V held in REGISTERS (128 VGPR/lane, loaded once) -> no
// per-step L2/LDS B-stream.  XU prefetched one step ahead.  sc0/sc1 IC
// exchange protocol unchanged from round 8 (proven correct).

typedef _Float16 f16;
typedef _Float16 f16x8 __attribute__((ext_vector_type(8)));
typedef float f32x4 __attribute__((ext_vector_type(4)));
typedef unsigned int u32;
typedef unsigned int u32x2 __attribute__((ext_vector_type(2)));
typedef unsigned int u32x4 __attribute__((ext_vector_type(4)));

#define BS 64
#define H  512
#define TSTEPS 256
#define KTOT 1024
#define GCOLS 2048
#define HSLOT (BS * H)          // f16 per time slot
#define HSLOT32 (HSLOT / 2)     // dwords per slot = 16384

// ---- static device scratch ----
__device__ f16  g_W16T[(size_t)GCOLS * KTOT];          // 4 MB: W^T[col][k] (k<512=U, >=512=V)
__device__ f16  g_xT[(size_t)TSTEPS * HSLOT];          // 16 MB
__device__ u32  g_hbuf32[(size_t)(TSTEPS + 1) * HSLOT32]; // 16.8 MB, dword view
__device__ float g_XU[(size_t)TSTEPS * BS * GCOLS];    // 128 MB: x@U + bias
__device__ int  g_flags[4][16];                        // per-group epoch flags

__global__ void prep_zero() {
  int i = blockIdx.x * 256 + threadIdx.x;
  if (i < HSLOT32) g_hbuf32[i] = 0u;
  if (i < 64) ((int*)g_flags)[i] = 0;
}

// ---- W16T[col][k] = (k<512 ? U[k][col] : V[k-512][col]) as fp16 ----
__global__ void build_w16t(const float* __restrict__ U, const float* __restrict__ V) {
  __shared__ float tile[32][33];
  int colT = blockIdx.x, kT = blockIdx.y;
  int x = threadIdx.x & 31, y = threadIdx.x >> 5;
  int col0 = colT * 32, k0 = kT * 32;
  for (int yy = y; yy < 32; yy += 8) {
    int k = k0 + yy;
    float v = (k < H) ? U[(size_t)k * GCOLS + col0 + x]
                      : V[(size_t)(k - H) * GCOLS + col0 + x];
    tile[yy][x] = v;
  }
  __syncthreads();
  for (int yy = y; yy < 32; yy += 8)
    g_W16T[(size_t)(col0 + yy) * KTOT + k0 + x] = (f16)tile[x][yy];
}

// ---- xT16[t][b][k] = x[b][k][t] as fp16 ----
__global__ void build_xt16(const float* __restrict__ x) {
  __shared__ float tile[32][33];
  int kt = blockIdx.x, tt = blockIdx.y, b = blockIdx.z;
  int xl = threadIdx.x & 31, y = threadIdx.x >> 5;
  int k0 = kt * 32, t0 = tt * 32;
  for (int yy = y; yy < 32; yy += 8)
    tile[yy][xl] = x[(size_t)b * (H * TSTEPS) + (size_t)(k0 + yy) * TSTEPS + t0 + xl];
  __syncthreads();
  for (int yy = y; yy < 32; yy += 8)
    g_xT[((size_t)(t0 + yy) * BS + b) * H + k0 + xl] = (f16)tile[xl][yy];
}

// ---- XU GEMM: g_XU[m][n] = xT[m][:512] @ U + bias ----
__global__ void xu_gemm(const float* __restrict__ bias) {
  const int tid  = threadIdx.x;
  const int lane = tid & 63;
  const int wv   = tid >> 6;
  const int l16  = lane & 15;
  const int lk8  = (lane >> 4) * 8;
  const int m0 = blockIdx.x * 64 + wv * 16;
  const int n0 = blockIdx.y * 64;

  const f16* Ap = g_xT + (size_t)(m0 + l16) * H + lk8;
  size_t bb[4];
  #pragma unroll
  for (int c = 0; c < 4; ++c)
    bb[c] = (size_t)(n0 + c * 16 + l16) * KTOT + lk8;

  f32x4 acc[4] = {};
  #pragma unroll 4
  for (int ki = 0; ki < 16; ++ki) {
    f16x8 a = *(const f16x8*)(Ap + ki * 32);
    #pragma unroll
    for (int c = 0; c < 4; ++c) {
      f16x8 b = *(const f16x8*)(g_W16T + bb[c] + ki * 32);
      acc[c] = __builtin_amdgcn_mfma_f32_16x16x32_f16(a, b, acc[c], 0, 0, 0);
    }
  }
  #pragma unroll
  for (int c = 0; c < 4; ++c) {
    float bv = bias[n0 + c * 16 + l16];
    #pragma unroll
    for (int i = 0; i < 4; ++i) {
      int m = m0 + (lane >> 4) * 4 + i;   // C/D: row=(lane>>4)*4+i, col=l16
      g_XU[(size_t)m * GCOLS + n0 + c * 16 + l16] = acc[c][i] + bv;
    }
  }
}

// ---------------- persistent recurrent kernel ----------------
// 64 blocks x 256 thr. grp = bid>>4 (16 samples), cb = bid&15 (32 units).
// Wave wv: u16 = wv&1 (16-unit subtile), kh = wv>>1 (K-half of 512).
// V fragments live in VGPRs (loaded once).  K-halves reduced via red[] LDS
// (round-2-proven).  All 4 gates of a (sample,unit) land in one kh0 lane.
__launch_bounds__(256, 1)
__global__ void lstm_rec(float* __restrict__ out_cT) {
  __shared__ __align__(16) char h_stage[16 * 1024];  // swizzled [16][512] f16
  __shared__ float red[2][4][256];                   // [u16][gate][lane*4+i]
  __shared__ f16 h_out2[16][32];                     // [sample][unit-in-block]

  const int tid  = threadIdx.x;
  const int lane = tid & 63;
  const int wv   = tid >> 6;
  const int u16  = wv & 1;
  const int kh   = wv >> 1;
  const int l16  = lane & 15;
  const int lk8  = (lane >> 4) * 8;      // k-elem offset (8 f16) within frag
  const int lk16 = (lane >> 4) * 16;     // same, in bytes
  const int grp  = blockIdx.x >> 4;
  const int cb   = blockIdx.x & 15;
  const int u0   = cb * 32;

  // ---- V fragments -> registers (once): col = g*512 + u0 + u16*16 + l16,
  //      k = 512 + kh*256 + lk8 + ki*32 ----
  f16x8 vfrag[4][8];
  #pragma unroll
  for (int g = 0; g < 4; ++g) {
    const f16* vp = g_W16T + (size_t)(g * H + u0 + u16 * 16 + l16) * KTOT
                  + H + kh * 256 + lk8;
    #pragma unroll
    for (int ki = 0; ki < 8; ++ki)
      vfrag[g][ki] = *(const f16x8*)(vp + ki * 32);
  }

  float c4[4] = {0.f, 0.f, 0.f, 0.f};
  float xu[4][4];
  // prologue: XU for t=0 (kh0 waves only use it)
  if (kh == 0) {
    #pragma unroll
    for (int i = 0; i < 4; ++i) {
      size_t row = (size_t)grp * 16 + (lane >> 4) * 4 + i;
      #pragma unroll
      for (int g = 0; g < 4; ++g)
        xu[g][i] = g_XU[row * GCOLS + g * H + u0 + u16 * 16 + l16];
    }
  }

  for (int t = 0; t < TSTEPS; ++t) {
    // --- wait for h[t] from all 16 blocks of this group ---
    if (t > 0) {
      if (wv == 0) {
        int spin = 0; bool done;
        do {
          int v = (lane < 16)
            ? __hip_atomic_load(&g_flags[grp][lane], __ATOMIC_RELAXED,
                                __HIP_MEMORY_SCOPE_SYSTEM)
            : t;
          done = __all(v >= t);
          if (!done) {
            if (++spin > (1 << 17)) break;   // safety hatch
            __builtin_amdgcn_s_sleep(1);
          }
        } while (!done);
      }
      __syncthreads();
    }

    // --- stage h[t] (16 KB) via batched bypass loads, one vmcnt drain ---
    {
      size_t base32 = (size_t)t * HSLOT32 + grp * 4096;
      const u32* p0 = g_hbuf32 + base32 + (size_t)tid * 4;
      const u32* p1 = p0 + 1024;
      const u32* p2 = p0 + 2048;
      const u32* p3 = p0 + 3072;
      u32x4 d0, d1, d2, d3;
      asm volatile(
        "global_load_dwordx4 %0, %4, off sc0 sc1\n\t"
        "global_load_dwordx4 %1, %5, off sc0 sc1\n\t"
        "global_load_dwordx4 %2, %6, off sc0 sc1\n\t"
        "global_load_dwordx4 %3, %7, off sc0 sc1\n\t"
        "s_waitcnt vmcnt(0)"
        : "=&v"(d0), "=&v"(d1), "=&v"(d2), "=&v"(d3)
        : "v"(p0), "v"(p1), "v"(p2), "v"(p3)
        : "memory");
      #pragma unroll
      for (int c = 0; c < 4; ++c) {
        int flat4 = c * 256 + tid;            // 16B-chunk index (0..1023)
        int s = flat4 >> 6;                   // sample row
        int byt = (flat4 & 63) * 16;          // byte offset within row
        u32x4 d = (c == 0) ? d0 : (c == 1) ? d1 : (c == 2) ? d2 : d3;
        *(u32x4*)&h_stage[s * 1024 + (byt ^ ((s & 7) << 4))] = d;
      }
    }
    __syncthreads();

    // --- h[t] @ V-regs: 4 gate-tiles, this wave's K-half (8 ki) ---
    f32x4 acc[4] = {};
    #pragma unroll
    for (int ki = 0; ki < 8; ++ki) {
      int abyte = l16 * 1024 + ((kh * 512 + ki * 64 + lk16) ^ ((l16 & 7) << 4));
      f16x8 a = *(const f16x8*)&h_stage[abyte];
      #pragma unroll
      for (int g = 0; g < 4; ++g)
        acc[g] = __builtin_amdgcn_mfma_f32_16x16x32_f16(a, vfrag[g][ki], acc[g], 0, 0, 0);
    }

    // --- prefetch XU for t+1 (hides under red/nonlin/publish/poll) ---
    float xu_n[4][4];
    if (kh == 0) {
      int tn = (t + 1 < TSTEPS) ? t + 1 : t;
      #pragma unroll
      for (int i = 0; i < 4; ++i) {
        size_t row = (size_t)tn * BS + grp * 16 + (lane >> 4) * 4 + i;
        #pragma unroll
        for (int g = 0; g < 4; ++g)
          xu_n[g][i] = g_XU[row * GCOLS + g * H + u0 + u16 * 16 + l16];
      }
    }

    // --- K-half reduction through LDS (round-2-proven) ---
    if (kh == 1) {
      #pragma unroll
      for (int g = 0; g < 4; ++g)
        *(f32x4*)&red[u16][g][lane * 4] = acc[g];
    }
    __syncthreads();

    if (kh == 0) {                  // reduce + nonlinearity + h_out
      #pragma unroll
      for (int i = 0; i < 4; ++i) {
        float gi = acc[0][i] + red[u16][0][lane * 4 + i] + xu[0][i];
        float gf = acc[1][i] + red[u16][1][lane * 4 + i] + xu[1][i];
        float gg = acc[2][i] + red[u16][2][lane * 4 + i] + xu[2][i];
        float go = acc[3][i] + red[u16][3][lane * 4 + i] + xu[3][i];
        float it = 1.f / (1.f + __expf(-gi));
        float ft = 1.f / (1.f + __expf(-gf));
        float gt = tanhf(gg);
        float ot = 1.f / (1.f + __expf(-go));
        float c  = ft * c4[i] + it * gt;
        c4[i] = c;
        float hh = ot * tanhf(c);
        int s = (lane >> 4) * 4 + i;          // C/D: row=(lane>>4)*4+i
        h_out2[s][u16 * 16 + l16] = (f16)hh;  //      col=lane&15
        if (t == TSTEPS - 1)
          out_cT[(size_t)(grp * 16 + s) * H + u0 + u16 * 16 + l16] = c;
      }
    }
    __syncthreads();

    // --- publish 1 KB via one bypass dword store/thread + single drain ---
    {
      int s  = tid >> 4;                     // sample row 0..15
      int dw = tid & 15;                     // dword within row's 32-unit chunk
      u32 v = *(const u32*)&h_out2[s][dw * 2];
      u32* dst = g_hbuf32 + (size_t)(t + 1) * HSLOT32
               + (size_t)(grp * 16 + s) * 256 + cb * 16 + dw;
      asm volatile(
        "global_store_dword %0, %1, off sc0 sc1\n\t"
        "s_waitcnt vmcnt(0)"
        :: "v"(dst), "v"(v)
        : "memory");
    }
    __syncthreads();   // all threads' stores are at IC
    if (tid == 0)
      __hip_atomic_store(&g_flags[grp][cb], t + 1, __ATOMIC_RELAXED,
                         __HIP_MEMORY_SCOPE_SYSTEM);

    // rotate XU double-buffer
    if (kh == 0) {
      #pragma unroll
      for (int g = 0; g < 4; ++g)
        #pragma unroll
        for (int i = 0; i < 4; ++i)
          xu[g][i] = xu_n[g][i];
    }
  }
}

// ---- finalize: out[b][j][t] = hbuf[t+1][b][j] ----
__global__ void finalize_seq(float* __restrict__ out) {
  __shared__ float tile[32][33];
  const f16* hb = (const f16*)g_hbuf32;
  int jt = blockIdx.x, tt = blockIdx.y, b = blockIdx.z;
  int xl = threadIdx.x & 31, y = threadIdx.x >> 5;
  int j0 = jt * 32, t0 = tt * 32;
  for (int yy = y; yy < 32; yy += 8)
    tile[yy][xl] = (float)hb[(size_t)(t0 + yy + 1) * HSLOT + (size_t)b * H + j0 + xl];
  __syncthreads();
  for (int yy = y; yy < 32; yy += 8)
    out[(size_t)b * (H * TSTEPS) + (size_t)(j0 + yy) * TSTEPS + t0 + xl] = tile[xl][yy];
}

__global__ void copy_hT(float* __restrict__ out_hT) {
  const f16* hb = (const f16*)g_hbuf32;
  int i = blockIdx.x * 256 + threadIdx.x;
  if (i < HSLOT) out_hT[i] = (float)hb[(size_t)TSTEPS * HSLOT + i];
}

// ---------------- host ----------------
extern "C" void kernel_launch(void* const* d_in, const int* in_sizes, int n_in,
                              void* d_out, int out_size, void* d_ws, size_t ws_size,
                              hipStream_t stream) {
  (void)in_sizes; (void)n_in; (void)d_ws; (void)ws_size; (void)out_size;
  const float* x    = (const float*)d_in[0];
  const float* U    = (const float*)d_in[1];
  const float* V    = (const float*)d_in[2];
  const float* bias = (const float*)d_in[3];
  float* out = (float*)d_out;

  float* out_hT = out + (size_t)BS * H * TSTEPS;
  float* out_cT = out_hT + (size_t)BS * H;

  prep_zero<<<dim3(65), dim3(256), 0, stream>>>();
  build_w16t<<<dim3(64, 32), dim3(256), 0, stream>>>(U, V);
  build_xt16<<<dim3(16, 8, 64), dim3(256), 0, stream>>>(x);
  xu_gemm<<<dim3(256, 32), dim3(256), 0, stream>>>(bias);
  lstm_rec<<<dim3(64), dim3(256), 0, stream>>>(out_cT);
  finalize_seq<<<dim3(16, 8, 64), dim3(256), 0, stream>>>(out);
  copy_hT<<<dim3(128), dim3(256), 0, stream>>>(out_hT);
}